// Round 2
// baseline (949.999 us; speedup 1.0000x reference)
//
#include <hip/hip_runtime.h>
#include <hip/hip_bf16.h>
#include <cstdint>

#define B_ 8
#define S_ 2048
#define E_ 1024

using u16 = unsigned short;

typedef __bf16 bf16x8 __attribute__((ext_vector_type(8)));
typedef float f32x4 __attribute__((ext_vector_type(4)));

__device__ inline u16 f2bf(float f) {
  uint32_t u = __float_as_uint(f);
  uint32_t r = (u + 0x7fffu + ((u >> 16) & 1u)) >> 16;
  return (u16)r;
}

// ---------------------------------------------------------------------------
// Generic NT GEMM: C[m,n] = sum_k A[m,k] * B[n,k]  (A,B bf16 row-major,
// K contiguous). 128x128 tile, BK=32, 4 waves each 64x64 via 4x4 of
// 16x16x32 MFMA. Staging via global_load_lds width=16 (m97 pattern).
// TRANS: store C transposed (idx = gn*ldc + gm), for writing V^T directly.
// ---------------------------------------------------------------------------
template<bool HAS_BIAS, bool RELU, bool HAS_RES, bool OUT_BF16, bool TRANS>
__global__ __launch_bounds__(256) void gemm_nt(
    const u16* __restrict__ A, const u16* __restrict__ B, void* __restrict__ C,
    const float* __restrict__ bias, const float* __restrict__ res,
    int lda, int ldb, int ldc, int K,
    long long strideA, long long strideB, long long strideC)
{
  __shared__ u16 lA[128 * 32];
  __shared__ u16 lB[128 * 32];

  const int tid  = threadIdx.x;
  const int lane = tid & 63;
  const int wave = tid >> 6;
  const int bm = blockIdx.y, bn = blockIdx.x, bz = blockIdx.z;

  const u16* Ab = A + (long long)bz * strideA;
  const u16* Bb = B + (long long)bz * strideB;

  const bool stageA = (wave < 2);
  const int  wpart  = (wave & 1) * 64;
  const int  srow   = lane >> 2;
  const int  scol   = (lane & 3) * 8;
  const int  ld     = stageA ? lda : ldb;
  const u16* gsrc   = stageA
      ? (Ab + (long long)(bm * 128 + wpart + srow) * lda + scol)
      : (Bb + (long long)(bn * 128 + wpart + srow) * ldb + scol);
  u16* ldst = (stageA ? lA : lB) + wpart * 32;

  f32x4 acc[4][4];
#pragma unroll
  for (int i = 0; i < 4; ++i)
#pragma unroll
    for (int j = 0; j < 4; ++j)
      acc[i][j] = (f32x4){0.f, 0.f, 0.f, 0.f};

  const int wm = (wave >> 1) * 64;
  const int wn = (wave & 1) * 64;
  const u16* pA = lA + (wm + (lane & 15)) * 32 + (lane >> 4) * 8;
  const u16* pB = lB + (wn + (lane & 15)) * 32 + (lane >> 4) * 8;

  const int nk = K >> 5;
  for (int kt = 0; kt < nk; ++kt) {
    __syncthreads();
    const u16* g = gsrc + kt * 32;
#pragma unroll
    for (int c = 0; c < 4; ++c) {
      __builtin_amdgcn_global_load_lds(
          (const __attribute__((address_space(1))) void*)(g + (long long)c * 16 * ld),
          (__attribute__((address_space(3))) void*)(ldst + c * 16 * 32),
          16, 0, 0);
    }
    __syncthreads();

    bf16x8 af[4], bfr[4];
#pragma unroll
    for (int i = 0; i < 4; ++i) af[i] = *(const bf16x8*)(pA + i * 16 * 32);
#pragma unroll
    for (int j = 0; j < 4; ++j) bfr[j] = *(const bf16x8*)(pB + j * 16 * 32);
#pragma unroll
    for (int i = 0; i < 4; ++i)
#pragma unroll
      for (int j = 0; j < 4; ++j)
        acc[i][j] = __builtin_amdgcn_mfma_f32_16x16x32_bf16(af[i], bfr[j], acc[i][j], 0, 0, 0);
  }

  // epilogue: C/D layout col = lane&15, row = (lane>>4)*4 + reg  [m89/m91]
  const int rb = wm + (lane >> 4) * 4;
  const int cb = wn + (lane & 15);
  const float* resb = (const float*)C;  // safe default
  if (HAS_RES) resb = res + (long long)bz * strideC;
  u16*   cb16 = (u16*)C   + (long long)bz * strideC;
  float* cf32 = (float*)C + (long long)bz * strideC;

#pragma unroll
  for (int j = 0; j < 4; ++j) {
    const int gn = bn * 128 + cb + j * 16;
    const float bvv = HAS_BIAS ? bias[gn] : 0.f;
#pragma unroll
    for (int i = 0; i < 4; ++i) {
#pragma unroll
      for (int r = 0; r < 4; ++r) {
        const int gm = bm * 128 + rb + i * 16 + r;
        const long long idx = TRANS ? ((long long)gn * ldc + gm)
                                    : ((long long)gm * ldc + gn);
        float v = acc[i][j][r] + bvv;
        if (RELU) v = fmaxf(v, 0.f);
        if (HAS_RES) v += resb[idx];
        if (OUT_BF16) cb16[idx] = f2bf(v);
        else          cf32[idx] = v;
      }
    }
  }
}

// ---------------------------------------------------------------------------
__global__ __launch_bounds__(256) void layernorm_kernel(
    const float* __restrict__ x, const float* __restrict__ w,
    const float* __restrict__ b, u16* __restrict__ out)
{
  const int row = blockIdx.x;
  const int tid = threadIdx.x;
  const float4 v = ((const float4*)(x + (long long)row * E_))[tid];
  float s  = v.x + v.y + v.z + v.w;
  float s2 = v.x * v.x + v.y * v.y + v.z * v.z + v.w * v.w;
#pragma unroll
  for (int o = 32; o >= 1; o >>= 1) { s += __shfl_xor(s, o); s2 += __shfl_xor(s2, o); }
  __shared__ float rs[4], rs2[4];
  const int wave = tid >> 6, lane = tid & 63;
  if (lane == 0) { rs[wave] = s; rs2[wave] = s2; }
  __syncthreads();
  s  = rs[0] + rs[1] + rs[2] + rs[3];
  s2 = rs2[0] + rs2[1] + rs2[2] + rs2[3];
  const float mu   = s * (1.f / E_);
  const float var  = s2 * (1.f / E_) - mu * mu;
  const float rstd = rsqrtf(var + 1e-5f);
  const float4 wv = ((const float4*)w)[tid];
  const float4 bv = ((const float4*)b)[tid];
  ushort4 o;
  o.x = f2bf((v.x - mu) * rstd * wv.x + bv.x);
  o.y = f2bf((v.y - mu) * rstd * wv.y + bv.y);
  o.z = f2bf((v.z - mu) * rstd * wv.z + bv.z);
  o.w = f2bf((v.w - mu) * rstd * wv.w + bv.w);
  ((ushort4*)(out + (long long)row * E_))[tid] = o;
}

// ---------------------------------------------------------------------------
// one block per score row: scale 1/32, column-mask, softmax, write bf16 P
__global__ __launch_bounds__(256) void softmax_kernel(
    const float* __restrict__ scores, const void* __restrict__ mask,
    const int* __restrict__ flag, u16* __restrict__ P, int b0, int rpb)
{
  const int row   = blockIdx.x;
  const int batch = b0 + row / rpb;
  const int tid   = threadIdx.x;
  const bool u8m  = (*flag != 0);
  const float* sr = scores + (long long)row * S_;
  const unsigned char* m8  = (const unsigned char*)mask + batch * S_;
  const int*           m32 = (const int*)mask + batch * S_;

  float vals[8];
  float mx = -3.0e38f;
#pragma unroll
  for (int t = 0; t < 2; ++t) {
    const float4 v = ((const float4*)sr)[tid + t * 256];
    const int k0 = (tid + t * 256) * 4;
    const float vv[4] = {v.x, v.y, v.z, v.w};
#pragma unroll
    for (int c = 0; c < 4; ++c) {
      const int k = k0 + c;
      const bool masked = u8m ? (m8[k] != 0) : (m32[k] != 0);
      const float val = masked ? -3.0e38f : vv[c] * 0.03125f;
      vals[t * 4 + c] = val;
      mx = fmaxf(mx, val);
    }
  }
#pragma unroll
  for (int o = 32; o >= 1; o >>= 1) mx = fmaxf(mx, __shfl_xor(mx, o));
  __shared__ float red[4];
  const int wave = tid >> 6, lane = tid & 63;
  if (lane == 0) red[wave] = mx;
  __syncthreads();
  mx = fmaxf(fmaxf(red[0], red[1]), fmaxf(red[2], red[3]));

  float s = 0.f;
#pragma unroll
  for (int i = 0; i < 8; ++i) { vals[i] = __expf(vals[i] - mx); s += vals[i]; }
#pragma unroll
  for (int o = 32; o >= 1; o >>= 1) s += __shfl_xor(s, o);
  __syncthreads();
  if (lane == 0) red[wave] = s;
  __syncthreads();
  s = red[0] + red[1] + red[2] + red[3];
  const float inv = 1.f / s;

  u16* pr = P + (long long)row * S_;
#pragma unroll
  for (int t = 0; t < 2; ++t) {
    ushort4 o;
    o.x = f2bf(vals[t * 4 + 0] * inv);
    o.y = f2bf(vals[t * 4 + 1] * inv);
    o.z = f2bf(vals[t * 4 + 2] * inv);
    o.w = f2bf(vals[t * 4 + 3] * inv);
    ((ushort4*)pr)[tid + t * 256] = o;
  }
}

// ---------------------------------------------------------------------------
__global__ __launch_bounds__(256) void convert_kernel(
    const float* __restrict__ in, u16* __restrict__ out, int n)
{
  const int i = blockIdx.x * 256 + threadIdx.x;
  if (i < n) out[i] = f2bf(in[i]);
}

// Detect pad_mask storage: int32 0/1 has zero bytes at i%4!=0; u8 does not.
__global__ void detect_kernel(const unsigned char* __restrict__ m, int* __restrict__ flag)
{
  __shared__ int any;
  if (threadIdx.x == 0) any = 0;
  __syncthreads();
  int loc = 0;
  for (int i = threadIdx.x; i < B_ * S_; i += 256)
    if ((i & 3) && m[i]) loc = 1;
  if (loc) atomicOr(&any, 1);
  __syncthreads();
  if (threadIdx.x == 0) *flag = any;
}

// ---------------------------------------------------------------------------
extern "C" void kernel_launch(void* const* d_in, const int* in_sizes, int n_in,
                              void* d_out, int out_size, void* d_ws, size_t ws_size,
                              hipStream_t stream)
{
  const float* x    = (const float*)d_in[0];
  const void*  mask = d_in[1];
  const float* ln1w = (const float*)d_in[2];
  const float* ln1b = (const float*)d_in[3];
  const float* ln2w = (const float*)d_in[4];
  const float* ln2b = (const float*)d_in[5];
  const float* Wq   = (const float*)d_in[6];
  const float* bq   = (const float*)d_in[7];
  const float* Wk   = (const float*)d_in[8];
  const float* bk   = (const float*)d_in[9];
  const float* Wv   = (const float*)d_in[10];
  const float* bv   = (const float*)d_in[11];
  const float* W1   = (const float*)d_in[12];
  const float* b1   = (const float*)d_in[13];
  const float* W2   = (const float*)d_in[14];
  const float* b2   = (const float*)d_in[15];

  const size_t MB = 1024ull * 1024ull;
  char* p = (char*)d_ws;
  int* flag    = (int*)p;   p += 256;
  u16* Wqb     = (u16*)p;   p += (size_t)E_ * E_ * 2;
  u16* Wkb     = (u16*)p;   p += (size_t)E_ * E_ * 2;
  u16* Wvb     = (u16*)p;   p += (size_t)E_ * E_ * 2;
  u16* W1b     = (u16*)p;   p += (size_t)2 * E_ * E_ * 2;
  u16* W2b     = (u16*)p;   p += (size_t)2 * E_ * E_ * 2;
  u16* normedb = (u16*)p;   p += (size_t)B_ * S_ * E_ * 2;
  char* chunk  = p;
  const size_t used = (size_t)(p - (char*)d_ws);
  const size_t avail = (ws_size > used) ? (ws_size - used) : 0;

  // --- pick attention chunking from available scratch ---
  // full-batch unit: Vt(4) + Q(4) + K(4) + scores(16) = 28 MB/batch; P aliases Q+K
  int bc = 0;
  for (int c = 8; c >= 1; c >>= 1)
    if (avail >= 28 * MB * (size_t)c) { bc = c; break; }
  int qc = S_;
  if (bc == 0) {
    bc = 1;
    qc = 128;
    // per-batch: K(4MB)+Vt(4MB) + qc*(Qrow 2KB + score-row 8KB + Prow 4KB)
    for (int q = 1024; q >= 128; q >>= 1)
      if (avail >= 8 * MB + (size_t)q * 14336) { qc = q; break; }
  }

  float* out = (float*)d_out;
  dim3 blk(256);

  detect_kernel<<<1, 256, 0, stream>>>((const unsigned char*)mask, flag);
  convert_kernel<<<(E_ * E_) / 256, blk, 0, stream>>>(Wq, Wqb, E_ * E_);
  convert_kernel<<<(E_ * E_) / 256, blk, 0, stream>>>(Wk, Wkb, E_ * E_);
  convert_kernel<<<(E_ * E_) / 256, blk, 0, stream>>>(Wv, Wvb, E_ * E_);
  convert_kernel<<<(2 * E_ * E_) / 256, blk, 0, stream>>>(W1, W1b, 2 * E_ * E_);
  convert_kernel<<<(2 * E_ * E_) / 256, blk, 0, stream>>>(W2, W2b, 2 * E_ * E_);

  layernorm_kernel<<<B_ * S_, blk, 0, stream>>>(x, ln1w, ln1b, normedb);

  for (int b0 = 0; b0 < B_; b0 += bc) {
    u16*   Vt = (u16*)chunk;                          // [bc][E][S]
    u16*   Qc = Vt + (size_t)bc * E_ * S_;            // [bc*qc][E]
    u16*   Kc = Qc + (size_t)bc * qc * E_;            // [bc][S][E]
    float* sc = (float*)(Kc + (size_t)bc * S_ * E_);  // [bc*qc][S]
    u16*   Pc = (qc == S_) ? Qc : (u16*)(sc + (size_t)bc * qc * S_);

    // K = normed @ Wk^T + bk  (flat M = bc*S)
    gemm_nt<true, false, false, true, false><<<dim3(E_ / 128, bc * S_ / 128, 1), blk, 0, stream>>>(
        normedb + (size_t)b0 * S_ * E_, Wkb, Kc, bk, nullptr, E_, E_, E_, E_, 0, 0, 0);
    // Vt = (normed @ Wv^T + bv)^T, batched z=bc
    gemm_nt<true, false, false, true, true><<<dim3(E_ / 128, S_ / 128, bc), blk, 0, stream>>>(
        normedb + (size_t)b0 * S_ * E_, Wvb, Vt, bv, nullptr, E_, E_, S_, E_,
        (long long)S_ * E_, 0, (long long)E_ * S_);

    for (int q0 = 0; q0 < S_; q0 += qc) {
      const int rowsQ = bc * qc;
      // Q = normed @ Wq^T + bq  (contiguous rows at b0*S + q0)
      gemm_nt<true, false, false, true, false><<<dim3(E_ / 128, rowsQ / 128, 1), blk, 0, stream>>>(
          normedb + ((size_t)b0 * S_ + q0) * E_, Wqb, Qc, bq, nullptr, E_, E_, E_, E_, 0, 0, 0);
      // scores = Q @ K^T  (batched z=bc, M=qc, N=S)
      gemm_nt<false, false, false, false, false><<<dim3(S_ / 128, qc / 128, bc), blk, 0, stream>>>(
          Qc, Kc, sc, nullptr, nullptr, E_, E_, S_, E_,
          (long long)qc * E_, (long long)S_ * E_, (long long)qc * S_);
      // softmax rows
      softmax_kernel<<<rowsQ, blk, 0, stream>>>(sc, mask, flag, Pc, b0, qc);
      // out = P @ Vt^T + x  (batched z=bc, M=qc, N=E)
      gemm_nt<false, false, true, false, false><<<dim3(E_ / 128, qc / 128, bc), blk, 0, stream>>>(
          Pc, Vt, out + ((size_t)b0 * S_ + q0) * E_, nullptr,
          x + ((size_t)b0 * S_ + q0) * E_, S_, S_, E_, S_,
          (long long)qc * S_, (long long)E_ * S_, (long long)S_ * E_);
    }
  }

  layernorm_kernel<<<B_ * S_, blk, 0, stream>>>(out, ln2w, ln2b, normedb);

  // FFN row-chunked: h[mr][2E] bf16 lives in the chunk region
  size_t mr_sz = avail / ((size_t)2 * E_ * 2);
  int mr = (int)((mr_sz > 16384) ? 16384 : mr_sz);
  mr &= ~127;
  if (mr < 128) mr = 128;
  u16* hb = (u16*)chunk;
  for (int m0 = 0; m0 < B_ * S_; m0 += mr) {
    const int mm = (B_ * S_ - m0 < mr) ? (B_ * S_ - m0) : mr;
    // h = relu(normed2 @ W1^T + b1)
    gemm_nt<true, true, false, true, false><<<dim3((2 * E_) / 128, mm / 128, 1), blk, 0, stream>>>(
        normedb + (size_t)m0 * E_, W1b, hb, b1, nullptr, E_, E_, 2 * E_, E_, 0, 0, 0);
    // out = h @ W2^T + b2 + out
    gemm_nt<true, false, true, false, false><<<dim3(E_ / 128, mm / 128, 1), blk, 0, stream>>>(
        hb, W2b, out + (size_t)m0 * E_, b2, out + (size_t)m0 * E_,
        2 * E_, 2 * E_, E_, 2 * E_, 0, 0, 0);
  }
}

// Round 3
// 865.446 us; speedup vs baseline: 1.0977x; 1.0977x over previous
//
#include <hip/hip_runtime.h>
#include <hip/hip_bf16.h>
#include <cstdint>

#define B_ 8
#define S_ 2048
#define E_ 1024

using u16 = unsigned short;

typedef __bf16 bf16x8 __attribute__((ext_vector_type(8)));
typedef float f32x4 __attribute__((ext_vector_type(4)));

__device__ inline u16 f2bf(float f) {
  uint32_t u = __float_as_uint(f);
  uint32_t r = (u + 0x7fffu + ((u >> 16) & 1u)) >> 16;
  return (u16)r;
}
__device__ inline float bf2f(u16 h) {
  return __uint_as_float(((uint32_t)h) << 16);
}

// ---------------------------------------------------------------------------
// Generic NT GEMM: C[m,n] = sum_k A[m,k] * B[n,k]  (A,B bf16 row-major,
// K contiguous). 128x128 tile, BK=32, 4 waves each 64x64 via 4x4 of
// 16x16x32 MFMA. Staging via global_load_lds width=16 (m97 pattern).
// TRANS: store C transposed (idx = gn*ldc + gm)  — for writing V^T directly.
// MASKSCALE: v = v/32; column-masked entries -> -3e38 (scores epilogue).
// ---------------------------------------------------------------------------
template<bool HAS_BIAS, bool RELU, bool HAS_RES, bool OUT_BF16, bool TRANS, bool MASKSCALE>
__global__ __launch_bounds__(256) void gemm_nt(
    const u16* __restrict__ A, const u16* __restrict__ B, void* __restrict__ C,
    const float* __restrict__ bias, const float* __restrict__ res,
    int lda, int ldb, int ldc, int K,
    long long strideA, long long strideB, long long strideC,
    const void* __restrict__ mask, const int* __restrict__ flag, int b0)
{
  __shared__ u16 lA[128 * 32];
  __shared__ u16 lB[128 * 32];

  const int tid  = threadIdx.x;
  const int lane = tid & 63;
  const int wave = tid >> 6;
  const int bm = blockIdx.y, bn = blockIdx.x, bz = blockIdx.z;

  const u16* Ab = A + (long long)bz * strideA;
  const u16* Bb = B + (long long)bz * strideB;

  const bool stageA = (wave < 2);
  const int  wpart  = (wave & 1) * 64;
  const int  srow   = lane >> 2;
  const int  scol   = (lane & 3) * 8;
  const int  ld     = stageA ? lda : ldb;
  const u16* gsrc   = stageA
      ? (Ab + (long long)(bm * 128 + wpart + srow) * lda + scol)
      : (Bb + (long long)(bn * 128 + wpart + srow) * ldb + scol);
  u16* ldst = (stageA ? lA : lB) + wpart * 32;

  f32x4 acc[4][4];
#pragma unroll
  for (int i = 0; i < 4; ++i)
#pragma unroll
    for (int j = 0; j < 4; ++j)
      acc[i][j] = (f32x4){0.f, 0.f, 0.f, 0.f};

  const int wm = (wave >> 1) * 64;
  const int wn = (wave & 1) * 64;
  const u16* pA = lA + (wm + (lane & 15)) * 32 + (lane >> 4) * 8;
  const u16* pB = lB + (wn + (lane & 15)) * 32 + (lane >> 4) * 8;

  const int nk = K >> 5;
  for (int kt = 0; kt < nk; ++kt) {
    __syncthreads();
    const u16* g = gsrc + kt * 32;
#pragma unroll
    for (int c = 0; c < 4; ++c) {
      __builtin_amdgcn_global_load_lds(
          (const __attribute__((address_space(1))) void*)(g + (long long)c * 16 * ld),
          (__attribute__((address_space(3))) void*)(ldst + c * 16 * 32),
          16, 0, 0);
    }
    __syncthreads();

    bf16x8 af[4], bfr[4];
#pragma unroll
    for (int i = 0; i < 4; ++i) af[i] = *(const bf16x8*)(pA + i * 16 * 32);
#pragma unroll
    for (int j = 0; j < 4; ++j) bfr[j] = *(const bf16x8*)(pB + j * 16 * 32);
#pragma unroll
    for (int i = 0; i < 4; ++i)
#pragma unroll
      for (int j = 0; j < 4; ++j)
        acc[i][j] = __builtin_amdgcn_mfma_f32_16x16x32_bf16(af[i], bfr[j], acc[i][j], 0, 0, 0);
  }

  // epilogue: C/D layout col = lane&15, row = (lane>>4)*4 + reg  [m89/m91]
  const int rb = wm + (lane >> 4) * 4;
  const int cb = wn + (lane & 15);
  const float* resb = (const float*)C;
  if (HAS_RES) resb = res + (long long)bz * strideC;
  u16*   cb16 = (u16*)C   + (long long)bz * strideC;
  float* cf32 = (float*)C + (long long)bz * strideC;

  bool u8m = false;
  const unsigned char* m8 = nullptr;
  const int* m32 = nullptr;
  if (MASKSCALE) {
    u8m = (*flag != 0);
    m8  = (const unsigned char*)mask + (long long)(b0 + bz) * S_;
    m32 = (const int*)mask + (long long)(b0 + bz) * S_;
  }

#pragma unroll
  for (int j = 0; j < 4; ++j) {
    const int gn = bn * 128 + cb + j * 16;
    const float bvv = HAS_BIAS ? bias[gn] : 0.f;
    bool masked = false;
    if (MASKSCALE) masked = u8m ? (m8[gn] != 0) : (m32[gn] != 0);
#pragma unroll
    for (int i = 0; i < 4; ++i) {
#pragma unroll
      for (int r = 0; r < 4; ++r) {
        const int gm = bm * 128 + rb + i * 16 + r;
        const long long idx = TRANS ? ((long long)gn * ldc + gm)
                                    : ((long long)gm * ldc + gn);
        float v = acc[i][j][r] + bvv;
        if (MASKSCALE) { v *= 0.03125f; if (masked) v = -3.0e38f; }
        if (RELU) v = fmaxf(v, 0.f);
        if (HAS_RES) v += resb[idx];
        if (OUT_BF16) cb16[idx] = f2bf(v);
        else          cf32[idx] = v;
      }
    }
  }
}

// ---------------------------------------------------------------------------
__global__ __launch_bounds__(256) void layernorm_kernel(
    const float* __restrict__ x, const float* __restrict__ w,
    const float* __restrict__ b, u16* __restrict__ out)
{
  const int row = blockIdx.x;
  const int tid = threadIdx.x;
  const float4 v = ((const float4*)(x + (long long)row * E_))[tid];
  float s  = v.x + v.y + v.z + v.w;
  float s2 = v.x * v.x + v.y * v.y + v.z * v.z + v.w * v.w;
#pragma unroll
  for (int o = 32; o >= 1; o >>= 1) { s += __shfl_xor(s, o); s2 += __shfl_xor(s2, o); }
  __shared__ float rs[4], rs2[4];
  const int wave = tid >> 6, lane = tid & 63;
  if (lane == 0) { rs[wave] = s; rs2[wave] = s2; }
  __syncthreads();
  s  = rs[0] + rs[1] + rs[2] + rs[3];
  s2 = rs2[0] + rs2[1] + rs2[2] + rs2[3];
  const float mu   = s * (1.f / E_);
  const float var  = s2 * (1.f / E_) - mu * mu;
  const float rstd = rsqrtf(var + 1e-5f);
  const float4 wv = ((const float4*)w)[tid];
  const float4 bv = ((const float4*)b)[tid];
  ushort4 o;
  o.x = f2bf((v.x - mu) * rstd * wv.x + bv.x);
  o.y = f2bf((v.y - mu) * rstd * wv.y + bv.y);
  o.z = f2bf((v.z - mu) * rstd * wv.z + bv.z);
  o.w = f2bf((v.w - mu) * rstd * wv.w + bv.w);
  ((ushort4*)(out + (long long)row * E_))[tid] = o;
}

// ---------------------------------------------------------------------------
// in-place softmax over one bf16 row of S_ (scale+mask already applied).
// 2048 bf16 = 256 threads x 8 elems (one uint4 each).
__global__ __launch_bounds__(256) void softmax_bf16_kernel(u16* __restrict__ sp)
{
  const int row = blockIdx.x;
  const int tid = threadIdx.x;
  u16* pr = sp + (long long)row * S_;
  uint4 raw = ((uint4*)pr)[tid];
  float v[8];
  const uint32_t w[4] = {raw.x, raw.y, raw.z, raw.w};
#pragma unroll
  for (int c = 0; c < 4; ++c) {
    v[2 * c]     = __uint_as_float(w[c] << 16);
    v[2 * c + 1] = __uint_as_float(w[c] & 0xffff0000u);
  }
  float mx = -3.38e38f;
#pragma unroll
  for (int i = 0; i < 8; ++i) mx = fmaxf(mx, v[i]);
#pragma unroll
  for (int o = 32; o >= 1; o >>= 1) mx = fmaxf(mx, __shfl_xor(mx, o));
  __shared__ float red[4];
  const int wave = tid >> 6, lane = tid & 63;
  if (lane == 0) red[wave] = mx;
  __syncthreads();
  mx = fmaxf(fmaxf(red[0], red[1]), fmaxf(red[2], red[3]));

  float s = 0.f;
#pragma unroll
  for (int i = 0; i < 8; ++i) { v[i] = __expf(v[i] - mx); s += v[i]; }
#pragma unroll
  for (int o = 32; o >= 1; o >>= 1) s += __shfl_xor(s, o);
  __syncthreads();
  if (lane == 0) red[wave] = s;
  __syncthreads();
  s = red[0] + red[1] + red[2] + red[3];
  const float inv = 1.f / s;

  uint4 o4;
  uint32_t* ow = (uint32_t*)&o4;
#pragma unroll
  for (int c = 0; c < 4; ++c) {
    const uint32_t lo = f2bf(v[2 * c] * inv);
    const uint32_t hi = f2bf(v[2 * c + 1] * inv);
    ow[c] = lo | (hi << 16);
  }
  ((uint4*)pr)[tid] = o4;
}

// ---------------------------------------------------------------------------
__global__ __launch_bounds__(256) void convert_kernel(
    const float* __restrict__ in, u16* __restrict__ out, int n)
{
  const int i = blockIdx.x * 256 + threadIdx.x;
  if (i < n) out[i] = f2bf(in[i]);
}

// Detect pad_mask storage: int32 0/1 has zero bytes at i%4!=0; u8 does not.
__global__ void detect_kernel(const unsigned char* __restrict__ m, int* __restrict__ flag)
{
  __shared__ int any;
  if (threadIdx.x == 0) any = 0;
  __syncthreads();
  int loc = 0;
  for (int i = threadIdx.x; i < B_ * S_; i += 256)
    if ((i & 3) && m[i]) loc = 1;
  if (loc) atomicOr(&any, 1);
  __syncthreads();
  if (threadIdx.x == 0) *flag = any;
}

// ---------------------------------------------------------------------------
extern "C" void kernel_launch(void* const* d_in, const int* in_sizes, int n_in,
                              void* d_out, int out_size, void* d_ws, size_t ws_size,
                              hipStream_t stream)
{
  const float* x    = (const float*)d_in[0];
  const void*  mask = d_in[1];
  const float* ln1w = (const float*)d_in[2];
  const float* ln1b = (const float*)d_in[3];
  const float* ln2w = (const float*)d_in[4];
  const float* ln2b = (const float*)d_in[5];
  const float* Wq   = (const float*)d_in[6];
  const float* bq   = (const float*)d_in[7];
  const float* Wk   = (const float*)d_in[8];
  const float* bk   = (const float*)d_in[9];
  const float* Wv   = (const float*)d_in[10];
  const float* bv   = (const float*)d_in[11];
  const float* W1   = (const float*)d_in[12];
  const float* b1   = (const float*)d_in[13];
  const float* W2   = (const float*)d_in[14];
  const float* b2   = (const float*)d_in[15];

  const size_t MB = 1024ull * 1024ull;
  char* p = (char*)d_ws;
  int* flag    = (int*)p;   p += 256;
  u16* Wqkb    = (u16*)p;   p += (size_t)2 * E_ * E_ * 2;   // [Wq;Wk] rows
  u16* Wvb     = (u16*)p;   p += (size_t)E_ * E_ * 2;
  u16* W1b     = (u16*)p;   p += (size_t)2 * E_ * E_ * 2;
  u16* W2b     = (u16*)p;   p += (size_t)2 * E_ * E_ * 2;
  float* bqk   = (float*)p; p += 2 * E_ * 4;
  u16* normedb = (u16*)p;   p += (size_t)B_ * S_ * E_ * 2;
  char* chunk  = p;
  const size_t used  = (size_t)(p - (char*)d_ws);
  const size_t avail = (ws_size > used) ? (ws_size - used) : 0;

  // per-batch chunk unit: QK [S,2E] 8MB + Vt [E,S] 4MB + scores/P [S,S] bf16 8MB
  int bc = 1;
  for (int c = 8; c >= 1; c >>= 1)
    if (avail >= 20 * MB * (size_t)c) { bc = c; break; }

  float* out = (float*)d_out;
  dim3 blk(256);

  detect_kernel<<<1, 256, 0, stream>>>((const unsigned char*)mask, flag);
  convert_kernel<<<(E_ * E_) / 256, blk, 0, stream>>>(Wq, Wqkb, E_ * E_);
  convert_kernel<<<(E_ * E_) / 256, blk, 0, stream>>>(Wk, Wqkb + (size_t)E_ * E_, E_ * E_);
  convert_kernel<<<(E_ * E_) / 256, blk, 0, stream>>>(Wv, Wvb, E_ * E_);
  convert_kernel<<<(2 * E_ * E_) / 256, blk, 0, stream>>>(W1, W1b, 2 * E_ * E_);
  convert_kernel<<<(2 * E_ * E_) / 256, blk, 0, stream>>>(W2, W2b, 2 * E_ * E_);
  hipMemcpyAsync(bqk, bq, E_ * sizeof(float), hipMemcpyDeviceToDevice, stream);
  hipMemcpyAsync(bqk + E_, bk, E_ * sizeof(float), hipMemcpyDeviceToDevice, stream);

  layernorm_kernel<<<B_ * S_, blk, 0, stream>>>(x, ln1w, ln1b, normedb);

  for (int b0 = 0; b0 < B_; b0 += bc) {
    u16* QKc = (u16*)chunk;                           // [bc*S][2E]
    u16* Vt  = QKc + (size_t)bc * S_ * 2 * E_;        // [bc][E][S]
    u16* Pc  = Vt + (size_t)bc * E_ * S_;             // [bc][S][S] scores->P

    // [Q|K] = normed @ [Wq;Wk]^T + bqk  (flat M = bc*S, N = 2E)
    gemm_nt<true, false, false, true, false, false>
        <<<dim3(2 * E_ / 128, bc * S_ / 128, 1), blk, 0, stream>>>(
        normedb + (size_t)b0 * S_ * E_, Wqkb, QKc, bqk, nullptr,
        E_, E_, 2 * E_, E_, 0, 0, 0, nullptr, nullptr, 0);

    // Vt = (normed @ Wv^T + bv)^T, batched z=bc
    gemm_nt<true, false, false, true, true, false>
        <<<dim3(E_ / 128, S_ / 128, bc), blk, 0, stream>>>(
        normedb + (size_t)b0 * S_ * E_, Wvb, Vt, bv, nullptr,
        E_, E_, S_, E_, (long long)S_ * E_, 0, (long long)E_ * S_,
        nullptr, nullptr, 0);

    // scores = (Q @ K^T)/32, masked, bf16  (batched z=bc, M=N=S)
    gemm_nt<false, false, false, true, false, true>
        <<<dim3(S_ / 128, S_ / 128, bc), blk, 0, stream>>>(
        QKc, QKc + E_, Pc, nullptr, nullptr,
        2 * E_, 2 * E_, S_, E_,
        (long long)S_ * 2 * E_, (long long)S_ * 2 * E_, (long long)S_ * S_,
        mask, flag, b0);

    // softmax in place
    softmax_bf16_kernel<<<bc * S_, blk, 0, stream>>>(Pc);

    // out = P @ Vt^T + x  (batched z=bc, M=S, N=E)
    gemm_nt<false, false, true, false, false, false>
        <<<dim3(E_ / 128, S_ / 128, bc), blk, 0, stream>>>(
        Pc, Vt, out + (size_t)b0 * S_ * E_, nullptr,
        x + (size_t)b0 * S_ * E_, S_, S_, E_, S_,
        (long long)S_ * S_, (long long)E_ * S_, (long long)S_ * E_,
        nullptr, nullptr, 0);
  }

  layernorm_kernel<<<B_ * S_, blk, 0, stream>>>(out, ln2w, ln2b, normedb);

  // FFN row-chunked: h[mr][2E] bf16 lives in the chunk region
  size_t mr_sz = avail / ((size_t)2 * E_ * 2);
  int mr = (int)((mr_sz > 16384) ? 16384 : mr_sz);
  mr &= ~127;
  if (mr < 128) mr = 128;
  u16* hb = (u16*)chunk;
  for (int m0 = 0; m0 < B_ * S_; m0 += mr) {
    const int mm = (B_ * S_ - m0 < mr) ? (B_ * S_ - m0) : mr;
    // h = relu(normed2 @ W1^T + b1)
    gemm_nt<true, true, false, true, false, false>
        <<<dim3((2 * E_) / 128, mm / 128, 1), blk, 0, stream>>>(
        normedb + (size_t)m0 * E_, W1b, hb, b1, nullptr,
        E_, E_, 2 * E_, E_, 0, 0, 0, nullptr, nullptr, 0);
    // out = h @ W2^T + b2 + out
    gemm_nt<true, false, true, false, false, false>
        <<<dim3(E_ / 128, mm / 128, 1), blk, 0, stream>>>(
        hb, W2b, out + (size_t)m0 * E_, b2, out + (size_t)m0 * E_,
        2 * E_, 2 * E_, E_, 2 * E_, 0, 0, 0, nullptr, nullptr, 0);
  }
}